// Round 1
// baseline (137719.116 us; speedup 1.0000x reference)
//
#include <hip/hip_runtime.h>
#include <stdint.h>

// Problem constants (from reference)
#define B_    16384
#define V_    64
#define DEMB_ 128
#define H_    512
#define PAD_  0
#define BOS_  1
#define EOS_  2

__device__ __forceinline__ uint32_t rotl32(uint32_t v, int n) {
    return (v << n) | (v >> (32 - n));
}

// JAX threefry2x32 (20 rounds), matches jax/_src/prng.py exactly.
__device__ __forceinline__ void tf2x32(uint32_t k0, uint32_t k1,
                                       uint32_t x0, uint32_t x1,
                                       uint32_t& o0, uint32_t& o1)
{
    const uint32_t k2 = k0 ^ k1 ^ 0x1BD11BDAu;
    x0 += k0; x1 += k1;
#define TFR(r) { x0 += x1; x1 = rotl32(x1, (r)); x1 ^= x0; }
    TFR(13) TFR(15) TFR(26) TFR(6)
    x0 += k1; x1 += k2 + 1u;
    TFR(17) TFR(29) TFR(16) TFR(24)
    x0 += k2; x1 += k0 + 2u;
    TFR(13) TFR(15) TFR(26) TFR(6)
    x0 += k0; x1 += k1 + 3u;
    TFR(17) TFR(29) TFR(16) TFR(24)
    x0 += k1; x1 += k2 + 4u;
    TFR(13) TFR(15) TFR(26) TFR(6)
    x0 += k2; x1 += k0 + 5u;
#undef TFR
    o0 = x0; o1 = x1;
}

__device__ __forceinline__ float sigm(float x) {
    return 1.0f / (1.0f + expf(-x));
}

// ---------------------------------------------------------------------------
// init: C0 = C1 = z @ W_l2h^T + b_l2h ; H0 = H1 = 0
// tile: 64 rows x 64 cols, K=128, 256 threads, 4x4 acc
// ---------------------------------------------------------------------------
__global__ __launch_bounds__(256)
void init_state(const float* __restrict__ z, const float* __restrict__ Wl,
                const float* __restrict__ bl,
                float* __restrict__ C0, float* __restrict__ C1,
                float* __restrict__ H0, float* __restrict__ H1)
{
    __shared__ __align__(16) float As[16][68];
    __shared__ __align__(16) float Bs[16][68];
    const int tid  = threadIdx.x;
    const int b0   = blockIdx.x * 64;
    const int j0   = blockIdx.y * 64;
    const int tx   = tid & 15, ty = tid >> 4;
    const int lrow = tid >> 2, lkq = tid & 3;

    float acc[4][4] = {};

    for (int kt = 0; kt < DEMB_ / 16; ++kt) {
        const int k0 = kt * 16;
        float4 av = *reinterpret_cast<const float4*>(z  + (size_t)(b0 + lrow) * DEMB_ + k0 + lkq * 4);
        float4 bv = *reinterpret_cast<const float4*>(Wl + (size_t)(j0 + lrow) * DEMB_ + k0 + lkq * 4);
        __syncthreads();
        As[lkq*4+0][lrow] = av.x; As[lkq*4+1][lrow] = av.y; As[lkq*4+2][lrow] = av.z; As[lkq*4+3][lrow] = av.w;
        Bs[lkq*4+0][lrow] = bv.x; Bs[lkq*4+1][lrow] = bv.y; Bs[lkq*4+2][lrow] = bv.z; Bs[lkq*4+3][lrow] = bv.w;
        __syncthreads();
#pragma unroll
        for (int kk = 0; kk < 16; ++kk) {
            float4 a4 = *reinterpret_cast<const float4*>(&As[kk][ty*4]);
            float4 b4 = *reinterpret_cast<const float4*>(&Bs[kk][tx*4]);
            float ar[4] = {a4.x, a4.y, a4.z, a4.w};
            float br[4] = {b4.x, b4.y, b4.z, b4.w};
#pragma unroll
            for (int r = 0; r < 4; ++r)
#pragma unroll
                for (int c = 0; c < 4; ++c)
                    acc[r][c] = fmaf(ar[r], br[c], acc[r][c]);
        }
    }

#pragma unroll
    for (int r = 0; r < 4; ++r) {
        const int b = b0 + ty * 4 + r;
        const int j = j0 + tx * 4;
        float v0 = acc[r][0] + bl[j+0];
        float v1 = acc[r][1] + bl[j+1];
        float v2 = acc[r][2] + bl[j+2];
        float v3 = acc[r][3] + bl[j+3];
        float4 cv = {v0, v1, v2, v3};
        float4 zz = {0.f, 0.f, 0.f, 0.f};
        *reinterpret_cast<float4*>(C0 + (size_t)b * H_ + j) = cv;
        *reinterpret_cast<float4*>(C1 + (size_t)b * H_ + j) = cv;
        *reinterpret_cast<float4*>(H0 + (size_t)b * H_ + j) = zz;
        *reinterpret_cast<float4*>(H1 + (size_t)b * H_ + j) = zz;
    }
}

__global__ __launch_bounds__(256)
void init_tokens(int* __restrict__ prevtok, int* __restrict__ isend)
{
    int i = blockIdx.x * 256 + threadIdx.x;
    if (i < B_) { prevtok[i] = BOS_; isend[i] = 0; }
}

// ---------------------------------------------------------------------------
// Fused LSTM layer: g = x@Wih^T + bih + h@Whh^T + bhh ; cell update.
// Block tile: 64 batch rows x 64 hidden units x all 4 gates.
// GATHER: x[b] = E[prev[b]] (layer 0), else x = Asrc rows (layer 1 input).
// C updated in place (each element touched by exactly one thread);
// H written to a separate buffer (ping-pong) to avoid read/write races.
// ---------------------------------------------------------------------------
template<int KX, bool GATHER>
__global__ __launch_bounds__(256)
void lstm_layer(const float* __restrict__ Asrc,
                const int*   __restrict__ prevtok,
                const float* __restrict__ Hrec,
                const float* __restrict__ Wih,   // [2048, KX]
                const float* __restrict__ Whh,   // [2048, 512]
                const float* __restrict__ bih,
                const float* __restrict__ bhh,
                float* __restrict__ Cst,
                float* __restrict__ Hout)
{
    __shared__ __align__(16) float As[16][68];
    __shared__ __align__(16) float Bs[4][16][68];
    __shared__ int rowtok[64];

    const int tid  = threadIdx.x;
    const int b0   = blockIdx.x * 64;
    const int j0   = blockIdx.y * 64;
    const int tx   = tid & 15, ty = tid >> 4;
    const int lrow = tid >> 2, lkq = tid & 3;

    if (GATHER) {
        if (tid < 64) rowtok[tid] = prevtok[b0 + tid];
    }
    __syncthreads();

    float acc[4][4][4] = {};

    const int NT = (KX + H_) / 16;
    for (int kt = 0; kt < NT; ++kt) {
        const int k0 = kt * 16;
        float4 av;
        float4 bv[4];
        if (k0 < KX) {
            const float* arow = GATHER ? (Asrc + (size_t)rowtok[lrow] * DEMB_)
                                       : (Asrc + (size_t)(b0 + lrow) * KX);
            av = *reinterpret_cast<const float4*>(arow + k0 + lkq * 4);
#pragma unroll
            for (int g = 0; g < 4; ++g)
                bv[g] = *reinterpret_cast<const float4*>(
                    Wih + (size_t)(g * H_ + j0 + lrow) * KX + k0 + lkq * 4);
        } else {
            const int kh = k0 - KX;
            av = *reinterpret_cast<const float4*>(Hrec + (size_t)(b0 + lrow) * H_ + kh + lkq * 4);
#pragma unroll
            for (int g = 0; g < 4; ++g)
                bv[g] = *reinterpret_cast<const float4*>(
                    Whh + (size_t)(g * H_ + j0 + lrow) * H_ + kh + lkq * 4);
        }
        __syncthreads();
        As[lkq*4+0][lrow] = av.x; As[lkq*4+1][lrow] = av.y; As[lkq*4+2][lrow] = av.z; As[lkq*4+3][lrow] = av.w;
#pragma unroll
        for (int g = 0; g < 4; ++g) {
            Bs[g][lkq*4+0][lrow] = bv[g].x; Bs[g][lkq*4+1][lrow] = bv[g].y;
            Bs[g][lkq*4+2][lrow] = bv[g].z; Bs[g][lkq*4+3][lrow] = bv[g].w;
        }
        __syncthreads();
#pragma unroll
        for (int kk = 0; kk < 16; ++kk) {
            float4 a4 = *reinterpret_cast<const float4*>(&As[kk][ty*4]);
            float ar[4] = {a4.x, a4.y, a4.z, a4.w};
#pragma unroll
            for (int g = 0; g < 4; ++g) {
                float4 b4 = *reinterpret_cast<const float4*>(&Bs[g][kk][tx*4]);
                float br[4] = {b4.x, b4.y, b4.z, b4.w};
#pragma unroll
                for (int r = 0; r < 4; ++r)
#pragma unroll
                    for (int c = 0; c < 4; ++c)
                        acc[g][r][c] = fmaf(ar[r], br[c], acc[g][r][c]);
            }
        }
    }

    // epilogue: cell update (i,f,g,o gate order, torch/jax convention)
    const int j = j0 + tx * 4;
#pragma unroll
    for (int r = 0; r < 4; ++r) {
        const int b = b0 + ty * 4 + r;
        float4 c4 = *reinterpret_cast<const float4*>(Cst + (size_t)b * H_ + j);
        float cold[4] = {c4.x, c4.y, c4.z, c4.w};
        float cn[4], hn[4];
#pragma unroll
        for (int c = 0; c < 4; ++c) {
            const int n = j + c;
            float gi = acc[0][r][c] + bih[n]          + bhh[n];
            float gf = acc[1][r][c] + bih[H_ + n]     + bhh[H_ + n];
            float gg = acc[2][r][c] + bih[2*H_ + n]   + bhh[2*H_ + n];
            float go = acc[3][r][c] + bih[3*H_ + n]   + bhh[3*H_ + n];
            float si = sigm(gi), sf = sigm(gf), so = sigm(go);
            float tg = tanhf(gg);
            // keep mul/add separate (no fma contraction) to mirror XLA elementwise
            float cc = __fadd_rn(__fmul_rn(sf, cold[c]), __fmul_rn(si, tg));
            cn[c] = cc;
            hn[c] = __fmul_rn(so, tanhf(cc));
        }
        float4 co = {cn[0], cn[1], cn[2], cn[3]};
        float4 ho = {hn[0], hn[1], hn[2], hn[3]};
        *reinterpret_cast<float4*>(Cst  + (size_t)b * H_ + j) = co;
        *reinterpret_cast<float4*>(Hout + (size_t)b * H_ + j) = ho;
    }
}

// ---------------------------------------------------------------------------
// logits = h1 @ W_out^T + b_out ; gumbel-argmax sampling (JAX categorical),
// EOS / PAD bookkeeping, token output. 64 rows per block.
// RNG: threefry partitionable mode (JAX >= 0.4.36 default):
//   key_t = threefry((0,42),(0,t)) ; bits[b,v] = fold_in xor of
//   threefry(key_t, (0, b*64+v)).
// ---------------------------------------------------------------------------
__global__ __launch_bounds__(256)
void sample_step(const float* __restrict__ H1src, const float* __restrict__ Wout,
                 const float* __restrict__ bout,
                 int* __restrict__ prevtok, int* __restrict__ isend,
                 int* __restrict__ out, int t, int T)
{
    __shared__ __align__(16) float As[16][68];
    __shared__ __align__(16) float Bs[16][68];
    __shared__ float LG[64][65];

    const int tid  = threadIdx.x;
    const int b0   = blockIdx.x * 64;
    const int tx   = tid & 15, ty = tid >> 4;
    const int lrow = tid >> 2, lkq = tid & 3;

    float acc[4][4] = {};

    for (int kt = 0; kt < H_ / 16; ++kt) {
        const int k0 = kt * 16;
        float4 av = *reinterpret_cast<const float4*>(H1src + (size_t)(b0 + lrow) * H_ + k0 + lkq * 4);
        float4 bv = *reinterpret_cast<const float4*>(Wout  + (size_t)lrow * H_ + k0 + lkq * 4);
        __syncthreads();
        As[lkq*4+0][lrow] = av.x; As[lkq*4+1][lrow] = av.y; As[lkq*4+2][lrow] = av.z; As[lkq*4+3][lrow] = av.w;
        Bs[lkq*4+0][lrow] = bv.x; Bs[lkq*4+1][lrow] = bv.y; Bs[lkq*4+2][lrow] = bv.z; Bs[lkq*4+3][lrow] = bv.w;
        __syncthreads();
#pragma unroll
        for (int kk = 0; kk < 16; ++kk) {
            float4 a4 = *reinterpret_cast<const float4*>(&As[kk][ty*4]);
            float4 b4 = *reinterpret_cast<const float4*>(&Bs[kk][tx*4]);
            float ar[4] = {a4.x, a4.y, a4.z, a4.w};
            float br[4] = {b4.x, b4.y, b4.z, b4.w};
#pragma unroll
            for (int r = 0; r < 4; ++r)
#pragma unroll
                for (int c = 0; c < 4; ++c)
                    acc[r][c] = fmaf(ar[r], br[c], acc[r][c]);
        }
    }

#pragma unroll
    for (int r = 0; r < 4; ++r)
#pragma unroll
        for (int c = 0; c < 4; ++c)
            LG[ty*4 + r][tx*4 + c] = acc[r][c] + bout[tx*4 + c];
    __syncthreads();

    const int wv = tid >> 6, lane = tid & 63;
    uint32_t kt0, kt1;
    tf2x32(0u, 42u, 0u, (uint32_t)t, kt0, kt1);   // fold-like split of key(42)

    const float TINY = 1.1754943508222875e-38f;   // finfo(f32).tiny
    for (int rr = 0; rr < 16; ++rr) {
        const int r = wv * 16 + rr;
        const int b = b0 + r;
        float lg = LG[r][lane];
        uint32_t r0, r1;
        tf2x32(kt0, kt1, 0u, (uint32_t)(b * V_ + lane), r0, r1);
        uint32_t bits = r0 ^ r1;                  // partitionable 32-bit fold
        float f = __uint_as_float((bits >> 9) | 0x3f800000u) - 1.0f;
        float u = fmaxf(TINY, __fadd_rn(f, TINY));
        float g = -logf(-logf(u));
        float val = __fadd_rn(g, lg);
        int idx = lane;
#pragma unroll
        for (int off = 32; off > 0; off >>= 1) {
            float ov = __shfl_xor(val, off, 64);
            int   oi = __shfl_xor(idx, off, 64);
            if (ov > val || (ov == val && oi < idx)) { val = ov; idx = oi; }
        }
        if (lane == 0) {
            int cur = idx;
            int e   = isend[b];
            int en  = e | (cur == EOS_);
            int tok = en ? PAD_ : cur;
            isend[b]   = en;
            prevtok[b] = tok;
            out[(size_t)b * T + t] = tok;
        }
    }
}

// ---------------------------------------------------------------------------
extern "C" void kernel_launch(void* const* d_in, const int* in_sizes, int n_in,
                              void* d_out, int out_size, void* d_ws, size_t ws_size,
                              hipStream_t stream)
{
    (void)in_sizes; (void)n_in; (void)ws_size;
    const float* z    = (const float*)d_in[0];
    const float* E    = (const float*)d_in[1];
    const float* Wl2h = (const float*)d_in[2];
    const float* bl2h = (const float*)d_in[3];
    const float* Wih0 = (const float*)d_in[4];
    const float* Whh0 = (const float*)d_in[5];
    const float* bih0 = (const float*)d_in[6];
    const float* bhh0 = (const float*)d_in[7];
    const float* Wih1 = (const float*)d_in[8];
    const float* Whh1 = (const float*)d_in[9];
    const float* bih1 = (const float*)d_in[10];
    const float* bhh1 = (const float*)d_in[11];
    const float* Wout = (const float*)d_in[12];
    const float* bout = (const float*)d_in[13];
    int* out = (int*)d_out;
    const int T = out_size / B_;   // 100

    char* w = (char*)d_ws;
    const size_t S = (size_t)B_ * H_ * sizeof(float);   // 33.55 MB
    float* C0  = (float*)(w + 0 * S);
    float* C1  = (float*)(w + 1 * S);
    float* H0A = (float*)(w + 2 * S);
    float* H0B = (float*)(w + 3 * S);
    float* H1A = (float*)(w + 4 * S);
    float* H1B = (float*)(w + 5 * S);
    int* prevtok = (int*)(w + 6 * S);
    int* isend   = (int*)(w + 6 * S + (size_t)B_ * sizeof(int));

    dim3 blk(256);
    init_state<<<dim3(B_/64, H_/64), blk, 0, stream>>>(z, Wl2h, bl2h, C0, C1, H0A, H1A);
    init_tokens<<<dim3(B_/256), blk, 0, stream>>>(prevtok, isend);

    float *h0c = H0A, *h0n = H0B, *h1c = H1A, *h1n = H1B;
    for (int t = 0; t < T; ++t) {
        lstm_layer<DEMB_, true><<<dim3(B_/64, H_/64), blk, 0, stream>>>(
            E, prevtok, h0c, Wih0, Whh0, bih0, bhh0, C0, h0n);
        lstm_layer<H_, false><<<dim3(B_/64, H_/64), blk, 0, stream>>>(
            h0n, nullptr, h1c, Wih1, Whh1, bih1, bhh1, C1, h1n);
        sample_step<<<dim3(B_/64), blk, 0, stream>>>(
            h1n, Wout, bout, prevtok, isend, out, t, T);
        float* tmp;
        tmp = h0c; h0c = h0n; h0n = tmp;
        tmp = h1c; h1c = h1n; h1n = tmp;
    }
}

// Round 2
// 134060.339 us; speedup vs baseline: 1.0273x; 1.0273x over previous
//
#include <hip/hip_runtime.h>
#include <stdint.h>

// Problem constants (from reference)
#define B_    16384
#define V_    64
#define DEMB_ 128
#define H_    512
#define PAD_  0
#define BOS_  1
#define EOS_  2

__device__ __forceinline__ uint32_t rotl32(uint32_t v, int n) {
    return (v << n) | (v >> (32 - n));
}

// JAX threefry2x32 (20 rounds), matches jax/_src/prng.py exactly.
__device__ __forceinline__ void tf2x32(uint32_t k0, uint32_t k1,
                                       uint32_t x0, uint32_t x1,
                                       uint32_t& o0, uint32_t& o1)
{
    const uint32_t k2 = k0 ^ k1 ^ 0x1BD11BDAu;
    x0 += k0; x1 += k1;
#define TFR(r) { x0 += x1; x1 = rotl32(x1, (r)); x1 ^= x0; }
    TFR(13) TFR(15) TFR(26) TFR(6)
    x0 += k1; x1 += k2 + 1u;
    TFR(17) TFR(29) TFR(16) TFR(24)
    x0 += k2; x1 += k0 + 2u;
    TFR(13) TFR(15) TFR(26) TFR(6)
    x0 += k0; x1 += k1 + 3u;
    TFR(17) TFR(29) TFR(16) TFR(24)
    x0 += k1; x1 += k2 + 4u;
    TFR(13) TFR(15) TFR(26) TFR(6)
    x0 += k2; x1 += k0 + 5u;
#undef TFR
    o0 = x0; o1 = x1;
}

__device__ __forceinline__ float sigm(float x) {
    return 1.0f / (1.0f + expf(-x));
}

// ---------------------------------------------------------------------------
// init: C0 = C1 = z @ W_l2h^T + b_l2h ; H0 = H1 = 0
// tile: 64 rows x 64 cols, K=128, 256 threads, 4x4 acc
// ---------------------------------------------------------------------------
__global__ __launch_bounds__(256)
void init_state(const float* __restrict__ z, const float* __restrict__ Wl,
                const float* __restrict__ bl,
                float* __restrict__ C0, float* __restrict__ C1,
                float* __restrict__ H0, float* __restrict__ H1)
{
    __shared__ __align__(16) float As[16][68];
    __shared__ __align__(16) float Bs[16][68];
    const int tid  = threadIdx.x;
    const int b0   = blockIdx.x * 64;
    const int j0   = blockIdx.y * 64;
    const int tx   = tid & 15, ty = tid >> 4;
    const int lrow = tid >> 2, lkq = tid & 3;

    float acc[4][4] = {};

    for (int kt = 0; kt < DEMB_ / 16; ++kt) {
        const int k0 = kt * 16;
        float4 av = *reinterpret_cast<const float4*>(z  + (size_t)(b0 + lrow) * DEMB_ + k0 + lkq * 4);
        float4 bv = *reinterpret_cast<const float4*>(Wl + (size_t)(j0 + lrow) * DEMB_ + k0 + lkq * 4);
        __syncthreads();
        As[lkq*4+0][lrow] = av.x; As[lkq*4+1][lrow] = av.y; As[lkq*4+2][lrow] = av.z; As[lkq*4+3][lrow] = av.w;
        Bs[lkq*4+0][lrow] = bv.x; Bs[lkq*4+1][lrow] = bv.y; Bs[lkq*4+2][lrow] = bv.z; Bs[lkq*4+3][lrow] = bv.w;
        __syncthreads();
#pragma unroll
        for (int kk = 0; kk < 16; ++kk) {
            float4 a4 = *reinterpret_cast<const float4*>(&As[kk][ty*4]);
            float4 b4 = *reinterpret_cast<const float4*>(&Bs[kk][tx*4]);
            float ar[4] = {a4.x, a4.y, a4.z, a4.w};
            float br[4] = {b4.x, b4.y, b4.z, b4.w};
#pragma unroll
            for (int r = 0; r < 4; ++r)
#pragma unroll
                for (int c = 0; c < 4; ++c)
                    acc[r][c] = fmaf(ar[r], br[c], acc[r][c]);
        }
    }

#pragma unroll
    for (int r = 0; r < 4; ++r) {
        const int b = b0 + ty * 4 + r;
        const int j = j0 + tx * 4;
        float v0 = acc[r][0] + bl[j+0];
        float v1 = acc[r][1] + bl[j+1];
        float v2 = acc[r][2] + bl[j+2];
        float v3 = acc[r][3] + bl[j+3];
        float4 cv = {v0, v1, v2, v3};
        float4 zz = {0.f, 0.f, 0.f, 0.f};
        *reinterpret_cast<float4*>(C0 + (size_t)b * H_ + j) = cv;
        *reinterpret_cast<float4*>(C1 + (size_t)b * H_ + j) = cv;
        *reinterpret_cast<float4*>(H0 + (size_t)b * H_ + j) = zz;
        *reinterpret_cast<float4*>(H1 + (size_t)b * H_ + j) = zz;
    }
}

__global__ __launch_bounds__(256)
void init_tokens(int* __restrict__ prevtok, int* __restrict__ isend)
{
    int i = blockIdx.x * 256 + threadIdx.x;
    if (i < B_) { prevtok[i] = BOS_; isend[i] = 0; }
}

// ---------------------------------------------------------------------------
// Fused LSTM layer: g = x@Wih^T + bih + h@Whh^T + bhh ; cell update.
// Block tile: 128 batch rows x 64 hidden units x all 4 gates (256 out cols).
// 256 threads; each thread: 8 rows x (4 gates x 4 cols) = 128 acc.
// Per kk: 6x ds_read_b128 (96B) feed 128 FMAs -> 0.375 B/FLOP (below LDS BW).
// k-loop: reg-staged double pipeline -- next-tile global loads issue BEFORE
// the compute phase so HBM/L2 latency hides under FMAs (T3 2-phase shape).
// Numerics: identical per-element k-order / cell math as the passing round-1
// kernel -> output stays bit-identical.
// ---------------------------------------------------------------------------
template<int KX, bool GATHER>
__global__ __launch_bounds__(256, 2)
void lstm_layer(const float* __restrict__ Asrc,
                const int*   __restrict__ prevtok,
                const float* __restrict__ Hrec,
                const float* __restrict__ Wih,   // [2048, KX]
                const float* __restrict__ Whh,   // [2048, 512]
                const float* __restrict__ bih,
                const float* __restrict__ bhh,
                float* __restrict__ Cst,
                float* __restrict__ Hout)
{
    __shared__ __align__(16) float As[16][132];      // [k][row], 128 rows
    __shared__ __align__(16) float Bs[4][16][68];    // [gate][k][unit]
    __shared__ int rowtok[128];

    const int tid  = threadIdx.x;
    const int b0   = blockIdx.x * 128;
    const int j0   = blockIdx.y * 64;
    const int tx   = tid & 15;        // col group (4 units)
    const int ty   = tid >> 4;        // row group (8 rows), 0..15
    const int srow = tid >> 1;        // staging row 0..127
    const int sk   = (tid & 1) * 8;   // staging k-half

    if (GATHER) {
        if (tid < 128) rowtok[tid] = prevtok[b0 + tid];
        __syncthreads();
    }

    const int NT = (KX + H_) / 16;

    float4 av[2], bv[4];
    // ---- load tile 0 into regs
    {
        const int k0 = 0;
        const float* arow = GATHER ? (Asrc + (size_t)rowtok[srow] * DEMB_)
                                   : (Asrc + (size_t)(b0 + srow) * KX);
        av[0] = *reinterpret_cast<const float4*>(arow + k0 + sk);
        av[1] = *reinterpret_cast<const float4*>(arow + k0 + sk + 4);
#pragma unroll
        for (int h = 0; h < 2; ++h) {
            const int grow = srow + h * 128;
            const int g = grow >> 6, u = grow & 63;
            const float* brow = Wih + (size_t)(g * H_ + j0 + u) * KX + k0 + sk;
            bv[h*2+0] = *reinterpret_cast<const float4*>(brow);
            bv[h*2+1] = *reinterpret_cast<const float4*>(brow + 4);
        }
    }

    float acc[4][8][4] = {};

    for (int kt = 0; kt < NT; ++kt) {
        __syncthreads();
        // ---- write staged regs to LDS (transposed)
        {
            float a0[4] = {av[0].x, av[0].y, av[0].z, av[0].w};
            float a1[4] = {av[1].x, av[1].y, av[1].z, av[1].w};
#pragma unroll
            for (int i = 0; i < 4; ++i) {
                As[sk + i][srow]     = a0[i];
                As[sk + 4 + i][srow] = a1[i];
            }
#pragma unroll
            for (int h = 0; h < 2; ++h) {
                const int grow = srow + h * 128;
                const int g = grow >> 6, u = grow & 63;
                float b0r[4] = {bv[h*2+0].x, bv[h*2+0].y, bv[h*2+0].z, bv[h*2+0].w};
                float b1r[4] = {bv[h*2+1].x, bv[h*2+1].y, bv[h*2+1].z, bv[h*2+1].w};
#pragma unroll
                for (int i = 0; i < 4; ++i) {
                    Bs[g][sk + i][u]     = b0r[i];
                    Bs[g][sk + 4 + i][u] = b1r[i];
                }
            }
        }
        __syncthreads();

        // ---- issue next-tile global loads (latency hides under FMAs below)
        if (kt + 1 < NT) {
            const int k0n = (kt + 1) * 16;
            if (k0n < KX) {
                const float* arow = GATHER ? (Asrc + (size_t)rowtok[srow] * DEMB_)
                                           : (Asrc + (size_t)(b0 + srow) * KX);
                av[0] = *reinterpret_cast<const float4*>(arow + k0n + sk);
                av[1] = *reinterpret_cast<const float4*>(arow + k0n + sk + 4);
#pragma unroll
                for (int h = 0; h < 2; ++h) {
                    const int grow = srow + h * 128;
                    const int g = grow >> 6, u = grow & 63;
                    const float* brow = Wih + (size_t)(g * H_ + j0 + u) * KX + k0n + sk;
                    bv[h*2+0] = *reinterpret_cast<const float4*>(brow);
                    bv[h*2+1] = *reinterpret_cast<const float4*>(brow + 4);
                }
            } else {
                const int kh = k0n - KX;
                av[0] = *reinterpret_cast<const float4*>(Hrec + (size_t)(b0 + srow) * H_ + kh + sk);
                av[1] = *reinterpret_cast<const float4*>(Hrec + (size_t)(b0 + srow) * H_ + kh + sk + 4);
#pragma unroll
                for (int h = 0; h < 2; ++h) {
                    const int grow = srow + h * 128;
                    const int g = grow >> 6, u = grow & 63;
                    const float* brow = Whh + (size_t)(g * H_ + j0 + u) * H_ + kh + sk;
                    bv[h*2+0] = *reinterpret_cast<const float4*>(brow);
                    bv[h*2+1] = *reinterpret_cast<const float4*>(brow + 4);
                }
            }
        }

        // ---- compute 16 kk from LDS
#pragma unroll 4
        for (int kk = 0; kk < 16; ++kk) {
            float4 a40 = *reinterpret_cast<const float4*>(&As[kk][ty*8]);
            float4 a41 = *reinterpret_cast<const float4*>(&As[kk][ty*8+4]);
            float ar[8] = {a40.x, a40.y, a40.z, a40.w, a41.x, a41.y, a41.z, a41.w};
#pragma unroll
            for (int g = 0; g < 4; ++g) {
                float4 b4 = *reinterpret_cast<const float4*>(&Bs[g][kk][tx*4]);
                float br[4] = {b4.x, b4.y, b4.z, b4.w};
#pragma unroll
                for (int r = 0; r < 8; ++r)
#pragma unroll
                    for (int c = 0; c < 4; ++c)
                        acc[g][r][c] = fmaf(ar[r], br[c], acc[g][r][c]);
            }
        }
    }

    // ---- epilogue: cell update (i,f,g,o gate order)
    const int j = j0 + tx * 4;
    float4 bi0 = *reinterpret_cast<const float4*>(bih + 0*H_ + j);
    float4 bi1 = *reinterpret_cast<const float4*>(bih + 1*H_ + j);
    float4 bi2 = *reinterpret_cast<const float4*>(bih + 2*H_ + j);
    float4 bi3 = *reinterpret_cast<const float4*>(bih + 3*H_ + j);
    float4 bh0 = *reinterpret_cast<const float4*>(bhh + 0*H_ + j);
    float4 bh1 = *reinterpret_cast<const float4*>(bhh + 1*H_ + j);
    float4 bh2 = *reinterpret_cast<const float4*>(bhh + 2*H_ + j);
    float4 bh3 = *reinterpret_cast<const float4*>(bhh + 3*H_ + j);
    float bi[4][4] = {{bi0.x,bi0.y,bi0.z,bi0.w},{bi1.x,bi1.y,bi1.z,bi1.w},
                      {bi2.x,bi2.y,bi2.z,bi2.w},{bi3.x,bi3.y,bi3.z,bi3.w}};
    float bh[4][4] = {{bh0.x,bh0.y,bh0.z,bh0.w},{bh1.x,bh1.y,bh1.z,bh1.w},
                      {bh2.x,bh2.y,bh2.z,bh2.w},{bh3.x,bh3.y,bh3.z,bh3.w}};

#pragma unroll
    for (int r = 0; r < 8; ++r) {
        const int b = b0 + ty * 8 + r;
        float4 c4 = *reinterpret_cast<const float4*>(Cst + (size_t)b * H_ + j);
        float cold[4] = {c4.x, c4.y, c4.z, c4.w};
        float cn[4], hn[4];
#pragma unroll
        for (int c = 0; c < 4; ++c) {
            float gi = acc[0][r][c] + bi[0][c] + bh[0][c];
            float gf = acc[1][r][c] + bi[1][c] + bh[1][c];
            float gg = acc[2][r][c] + bi[2][c] + bh[2][c];
            float go = acc[3][r][c] + bi[3][c] + bh[3][c];
            float si = sigm(gi), sf = sigm(gf), so = sigm(go);
            float tg = tanhf(gg);
            // keep mul/add separate (no fma contraction) to mirror XLA elementwise
            float cc = __fadd_rn(__fmul_rn(sf, cold[c]), __fmul_rn(si, tg));
            cn[c] = cc;
            hn[c] = __fmul_rn(so, tanhf(cc));
        }
        float4 co = {cn[0], cn[1], cn[2], cn[3]};
        float4 ho = {hn[0], hn[1], hn[2], hn[3]};
        *reinterpret_cast<float4*>(Cst  + (size_t)b * H_ + j) = co;
        *reinterpret_cast<float4*>(Hout + (size_t)b * H_ + j) = ho;
    }
}

// ---------------------------------------------------------------------------
// logits = h1 @ W_out^T + b_out ; gumbel-argmax sampling (JAX categorical),
// EOS / PAD bookkeeping, token output. 64 rows per block.
// RNG: threefry partitionable mode (JAX >= 0.4.36 default).
// ---------------------------------------------------------------------------
__global__ __launch_bounds__(256)
void sample_step(const float* __restrict__ H1src, const float* __restrict__ Wout,
                 const float* __restrict__ bout,
                 int* __restrict__ prevtok, int* __restrict__ isend,
                 int* __restrict__ out, int t, int T)
{
    __shared__ __align__(16) float As[16][68];
    __shared__ __align__(16) float Bs[16][68];
    __shared__ float LG[64][65];

    const int tid  = threadIdx.x;
    const int b0   = blockIdx.x * 64;
    const int tx   = tid & 15, ty = tid >> 4;
    const int lrow = tid >> 2, lkq = tid & 3;

    float acc[4][4] = {};

    for (int kt = 0; kt < H_ / 16; ++kt) {
        const int k0 = kt * 16;
        float4 av = *reinterpret_cast<const float4*>(H1src + (size_t)(b0 + lrow) * H_ + k0 + lkq * 4);
        float4 bv = *reinterpret_cast<const float4*>(Wout  + (size_t)lrow * H_ + k0 + lkq * 4);
        __syncthreads();
        As[lkq*4+0][lrow] = av.x; As[lkq*4+1][lrow] = av.y; As[lkq*4+2][lrow] = av.z; As[lkq*4+3][lrow] = av.w;
        Bs[lkq*4+0][lrow] = bv.x; Bs[lkq*4+1][lrow] = bv.y; Bs[lkq*4+2][lrow] = bv.z; Bs[lkq*4+3][lrow] = bv.w;
        __syncthreads();
#pragma unroll
        for (int kk = 0; kk < 16; ++kk) {
            float4 a4 = *reinterpret_cast<const float4*>(&As[kk][ty*4]);
            float4 b4 = *reinterpret_cast<const float4*>(&Bs[kk][tx*4]);
            float ar[4] = {a4.x, a4.y, a4.z, a4.w};
            float br[4] = {b4.x, b4.y, b4.z, b4.w};
#pragma unroll
            for (int r = 0; r < 4; ++r)
#pragma unroll
                for (int c = 0; c < 4; ++c)
                    acc[r][c] = fmaf(ar[r], br[c], acc[r][c]);
        }
    }

#pragma unroll
    for (int r = 0; r < 4; ++r)
#pragma unroll
        for (int c = 0; c < 4; ++c)
            LG[ty*4 + r][tx*4 + c] = acc[r][c] + bout[tx*4 + c];
    __syncthreads();

    const int wv = tid >> 6, lane = tid & 63;
    uint32_t kt0, kt1;
    tf2x32(0u, 42u, 0u, (uint32_t)t, kt0, kt1);   // fold-like split of key(42)

    const float TINY = 1.1754943508222875e-38f;   // finfo(f32).tiny
    for (int rr = 0; rr < 16; ++rr) {
        const int r = wv * 16 + rr;
        const int b = b0 + r;
        float lg = LG[r][lane];
        uint32_t r0, r1;
        tf2x32(kt0, kt1, 0u, (uint32_t)(b * V_ + lane), r0, r1);
        uint32_t bits = r0 ^ r1;                  // partitionable 32-bit fold
        float f = __uint_as_float((bits >> 9) | 0x3f800000u) - 1.0f;
        float u = fmaxf(TINY, __fadd_rn(f, TINY));
        float g = -logf(-logf(u));
        float val = __fadd_rn(g, lg);
        int idx = lane;
#pragma unroll
        for (int off = 32; off > 0; off >>= 1) {
            float ov = __shfl_xor(val, off, 64);
            int   oi = __shfl_xor(idx, off, 64);
            if (ov > val || (ov == val && oi < idx)) { val = ov; idx = oi; }
        }
        if (lane == 0) {
            int cur = idx;
            int e   = isend[b];
            int en  = e | (cur == EOS_);
            int tok = en ? PAD_ : cur;
            isend[b]   = en;
            prevtok[b] = tok;
            out[(size_t)b * T + t] = tok;
        }
    }
}

// ---------------------------------------------------------------------------
extern "C" void kernel_launch(void* const* d_in, const int* in_sizes, int n_in,
                              void* d_out, int out_size, void* d_ws, size_t ws_size,
                              hipStream_t stream)
{
    (void)in_sizes; (void)n_in; (void)ws_size;
    const float* z    = (const float*)d_in[0];
    const float* E    = (const float*)d_in[1];
    const float* Wl2h = (const float*)d_in[2];
    const float* bl2h = (const float*)d_in[3];
    const float* Wih0 = (const float*)d_in[4];
    const float* Whh0 = (const float*)d_in[5];
    const float* bih0 = (const float*)d_in[6];
    const float* bhh0 = (const float*)d_in[7];
    const float* Wih1 = (const float*)d_in[8];
    const float* Whh1 = (const float*)d_in[9];
    const float* bih1 = (const float*)d_in[10];
    const float* bhh1 = (const float*)d_in[11];
    const float* Wout = (const float*)d_in[12];
    const float* bout = (const float*)d_in[13];
    int* out = (int*)d_out;
    const int T = out_size / B_;   // 100

    char* w = (char*)d_ws;
    const size_t S = (size_t)B_ * H_ * sizeof(float);   // 33.55 MB
    float* C0  = (float*)(w + 0 * S);
    float* C1  = (float*)(w + 1 * S);
    float* H0A = (float*)(w + 2 * S);
    float* H0B = (float*)(w + 3 * S);
    float* H1A = (float*)(w + 4 * S);
    float* H1B = (float*)(w + 5 * S);
    int* prevtok = (int*)(w + 6 * S);
    int* isend   = (int*)(w + 6 * S + (size_t)B_ * sizeof(int));

    dim3 blk(256);
    init_state<<<dim3(B_/64, H_/64), blk, 0, stream>>>(z, Wl2h, bl2h, C0, C1, H0A, H1A);
    init_tokens<<<dim3(B_/256), blk, 0, stream>>>(prevtok, isend);

    float *h0c = H0A, *h0n = H0B, *h1c = H1A, *h1n = H1B;
    for (int t = 0; t < T; ++t) {
        lstm_layer<DEMB_, true><<<dim3(B_/128, H_/64), blk, 0, stream>>>(
            E, prevtok, h0c, Wih0, Whh0, bih0, bhh0, C0, h0n);
        lstm_layer<H_, false><<<dim3(B_/128, H_/64), blk, 0, stream>>>(
            h0n, nullptr, h1c, Wih1, Whh1, bih1, bhh1, C1, h1n);
        sample_step<<<dim3(B_/64), blk, 0, stream>>>(
            h1n, Wout, bout, prevtok, isend, out, t, T);
        float* tmp;
        tmp = h0c; h0c = h0n; h0n = tmp;
        tmp = h1c; h1c = h1n; h1n = tmp;
    }
}

// Round 3
// 132070.642 us; speedup vs baseline: 1.0428x; 1.0151x over previous
//
#include <hip/hip_runtime.h>
#include <stdint.h>

// Problem constants (from reference)
#define B_    16384
#define V_    64
#define DEMB_ 128
#define H_    512
#define PAD_  0
#define BOS_  1
#define EOS_  2

__device__ __forceinline__ uint32_t rotl32(uint32_t v, int n) {
    return (v << n) | (v >> (32 - n));
}

// JAX threefry2x32 (20 rounds), matches jax/_src/prng.py exactly.
__device__ __forceinline__ void tf2x32(uint32_t k0, uint32_t k1,
                                       uint32_t x0, uint32_t x1,
                                       uint32_t& o0, uint32_t& o1)
{
    const uint32_t k2 = k0 ^ k1 ^ 0x1BD11BDAu;
    x0 += k0; x1 += k1;
#define TFR(r) { x0 += x1; x1 = rotl32(x1, (r)); x1 ^= x0; }
    TFR(13) TFR(15) TFR(26) TFR(6)
    x0 += k1; x1 += k2 + 1u;
    TFR(17) TFR(29) TFR(16) TFR(24)
    x0 += k2; x1 += k0 + 2u;
    TFR(13) TFR(15) TFR(26) TFR(6)
    x0 += k0; x1 += k1 + 3u;
    TFR(17) TFR(29) TFR(16) TFR(24)
    x0 += k1; x1 += k2 + 4u;
    TFR(13) TFR(15) TFR(26) TFR(6)
    x0 += k2; x1 += k0 + 5u;
#undef TFR
    o0 = x0; o1 = x1;
}

__device__ __forceinline__ float sigm(float x) {
    return 1.0f / (1.0f + expf(-x));
}

__device__ __forceinline__ float4 ld4(const float* p) {
    return *reinterpret_cast<const float4*>(p);
}

// ---------------------------------------------------------------------------
// init: C0 = C1 = z @ W_l2h^T + b_l2h ; H0 = H1 = 0
// ---------------------------------------------------------------------------
__global__ __launch_bounds__(256)
void init_state(const float* __restrict__ z, const float* __restrict__ Wl,
                const float* __restrict__ bl,
                float* __restrict__ C0, float* __restrict__ C1,
                float* __restrict__ H0, float* __restrict__ H1)
{
    __shared__ __align__(16) float As[16][68];
    __shared__ __align__(16) float Bs[16][68];
    const int tid  = threadIdx.x;
    const int b0   = blockIdx.x * 64;
    const int j0   = blockIdx.y * 64;
    const int tx   = tid & 15, ty = tid >> 4;
    const int lrow = tid >> 2, lkq = tid & 3;

    float acc[4][4] = {};

    for (int kt = 0; kt < DEMB_ / 16; ++kt) {
        const int k0 = kt * 16;
        float4 av = ld4(z  + (size_t)(b0 + lrow) * DEMB_ + k0 + lkq * 4);
        float4 bv = ld4(Wl + (size_t)(j0 + lrow) * DEMB_ + k0 + lkq * 4);
        __syncthreads();
        As[lkq*4+0][lrow] = av.x; As[lkq*4+1][lrow] = av.y; As[lkq*4+2][lrow] = av.z; As[lkq*4+3][lrow] = av.w;
        Bs[lkq*4+0][lrow] = bv.x; Bs[lkq*4+1][lrow] = bv.y; Bs[lkq*4+2][lrow] = bv.z; Bs[lkq*4+3][lrow] = bv.w;
        __syncthreads();
#pragma unroll
        for (int kk = 0; kk < 16; ++kk) {
            float4 a4 = ld4(&As[kk][ty*4]);
            float4 b4 = ld4(&Bs[kk][tx*4]);
            float ar[4] = {a4.x, a4.y, a4.z, a4.w};
            float br[4] = {b4.x, b4.y, b4.z, b4.w};
#pragma unroll
            for (int r = 0; r < 4; ++r)
#pragma unroll
                for (int c = 0; c < 4; ++c)
                    acc[r][c] = fmaf(ar[r], br[c], acc[r][c]);
        }
    }

#pragma unroll
    for (int r = 0; r < 4; ++r) {
        const int b = b0 + ty * 4 + r;
        const int j = j0 + tx * 4;
        float4 cv = {acc[r][0] + bl[j+0], acc[r][1] + bl[j+1],
                     acc[r][2] + bl[j+2], acc[r][3] + bl[j+3]};
        float4 zz = {0.f, 0.f, 0.f, 0.f};
        *reinterpret_cast<float4*>(C0 + (size_t)b * H_ + j) = cv;
        *reinterpret_cast<float4*>(C1 + (size_t)b * H_ + j) = cv;
        *reinterpret_cast<float4*>(H0 + (size_t)b * H_ + j) = zz;
        *reinterpret_cast<float4*>(H1 + (size_t)b * H_ + j) = zz;
    }
}

__global__ __launch_bounds__(256)
void init_tokens(int* __restrict__ prevtok, int* __restrict__ isend)
{
    int i = blockIdx.x * 256 + threadIdx.x;
    if (i < B_) { prevtok[i] = BOS_; isend[i] = 0; }
}

// ---------------------------------------------------------------------------
// Fused LSTM layer, deep-pipelined:
//   - 128 batch rows x 64 units x 4 gates per block, 256 threads, acc 4x8x4.
//   - double-buffered LDS, ONE __syncthreads per K-tile.
//   - steady state: ds_write buf[nxt] (regs loaded a full iter ago -> no
//     vmcnt stall), issue loads for tile kt+2, compute buf[cur], barrier.
//   - XCD swizzle: j-block = bid&7 -> each XCD keeps its weight slice in L2.
// Numerics: identical per-element k-order as passing rounds -> bit-identical.
// ---------------------------------------------------------------------------
template<int KX, bool GATHER>
__global__ __launch_bounds__(256, 2)
void lstm_layer(const float* __restrict__ Asrc,
                const int*   __restrict__ prevtok,
                const float* __restrict__ Hrec,
                const float* __restrict__ Wih,   // [2048, KX]
                const float* __restrict__ Whh,   // [2048, 512]
                const float* __restrict__ bih,
                const float* __restrict__ bhh,
                float* __restrict__ Cst,
                float* __restrict__ Hout)
{
    __shared__ __align__(16) float As[2][16][132];     // [buf][k][row]
    __shared__ __align__(16) float Bs[2][4][16][68];   // [buf][gate][k][unit]
    __shared__ int rowtok[128];

    const int tid  = threadIdx.x;
    const int bid  = blockIdx.x;
    const int b0   = (bid >> 3) * 128;     // batch block
    const int j0   = (bid & 7) * 64;       // unit block -> XCD-affine
    const int tx   = tid & 15;             // col group (4 units)
    const int ty   = tid >> 4;             // row group (8 rows)
    const int srow = tid >> 1;             // staging row 0..127
    const int sk   = (tid & 1) * 8;        // staging k-half

    if (GATHER) {
        if (tid < 128) rowtok[tid] = prevtok[b0 + tid];
        __syncthreads();
    }

    // staging role: this thread loads rows (g0,u0) and (g1,u1) of the weight tile
    const int grow0 = srow, grow1 = srow + 128;
    const int g0 = grow0 >> 6, u0 = grow0 & 63;
    const int g1 = grow1 >> 6, u1 = grow1 & 63;

    const float* arowA = GATHER ? (Asrc + (size_t)rowtok[srow] * DEMB_)
                                : (Asrc + (size_t)(b0 + srow) * KX);
    const float* arowH = Hrec + (size_t)(b0 + srow) * H_;
    const float* browA0 = Wih + (size_t)(g0 * H_ + j0 + u0) * KX;
    const float* browA1 = Wih + (size_t)(g1 * H_ + j0 + u1) * KX;
    const float* browH0 = Whh + (size_t)(g0 * H_ + j0 + u0) * H_;
    const float* browH1 = Whh + (size_t)(g1 * H_ + j0 + u1) * H_;

    const int NT = (KX + H_) / 16;

    float4 av[2], bv[4];

    auto load_tile = [&](int kt) {
        const int k0 = kt * 16;
        if (k0 < KX) {
            av[0] = ld4(arowA + k0 + sk);
            av[1] = ld4(arowA + k0 + sk + 4);
            bv[0] = ld4(browA0 + k0 + sk);
            bv[1] = ld4(browA0 + k0 + sk + 4);
            bv[2] = ld4(browA1 + k0 + sk);
            bv[3] = ld4(browA1 + k0 + sk + 4);
        } else {
            const int kh = k0 - KX;
            av[0] = ld4(arowH + kh + sk);
            av[1] = ld4(arowH + kh + sk + 4);
            bv[0] = ld4(browH0 + kh + sk);
            bv[1] = ld4(browH0 + kh + sk + 4);
            bv[2] = ld4(browH1 + kh + sk);
            bv[3] = ld4(browH1 + kh + sk + 4);
        }
    };

    auto write_tile = [&](int p) {
        float a0[4] = {av[0].x, av[0].y, av[0].z, av[0].w};
        float a1[4] = {av[1].x, av[1].y, av[1].z, av[1].w};
#pragma unroll
        for (int i = 0; i < 4; ++i) {
            As[p][sk + i][srow]     = a0[i];
            As[p][sk + 4 + i][srow] = a1[i];
        }
        float b0r[4] = {bv[0].x, bv[0].y, bv[0].z, bv[0].w};
        float b1r[4] = {bv[1].x, bv[1].y, bv[1].z, bv[1].w};
        float b2r[4] = {bv[2].x, bv[2].y, bv[2].z, bv[2].w};
        float b3r[4] = {bv[3].x, bv[3].y, bv[3].z, bv[3].w};
#pragma unroll
        for (int i = 0; i < 4; ++i) {
            Bs[p][g0][sk + i][u0]     = b0r[i];
            Bs[p][g0][sk + 4 + i][u0] = b1r[i];
            Bs[p][g1][sk + i][u1]     = b2r[i];
            Bs[p][g1][sk + 4 + i][u1] = b3r[i];
        }
    };

    // ---- prologue: tile0 -> buf0; issue tile1 loads; barrier
    load_tile(0);
    write_tile(0);
    load_tile(1);
    __syncthreads();

    float acc[4][8][4] = {};

    for (int kt = 0; kt < NT; ++kt) {
        const int cur = kt & 1;
        // 1. write next tile (regs loaded one full iteration ago -> arrived)
        if (kt + 1 < NT) {
            write_tile(cur ^ 1);
            // 2. issue loads for tile kt+2 (latency hidden by compute below)
            if (kt + 2 < NT) load_tile(kt + 2);
        }
        // 3. compute current tile from LDS
#pragma unroll 4
        for (int kk = 0; kk < 16; ++kk) {
            float4 a40 = ld4(&As[cur][kk][ty*8]);
            float4 a41 = ld4(&As[cur][kk][ty*8+4]);
            float ar[8] = {a40.x, a40.y, a40.z, a40.w, a41.x, a41.y, a41.z, a41.w};
#pragma unroll
            for (int g = 0; g < 4; ++g) {
                float4 b4 = ld4(&Bs[cur][g][kk][tx*4]);
                float br[4] = {b4.x, b4.y, b4.z, b4.w};
#pragma unroll
                for (int r = 0; r < 8; ++r)
#pragma unroll
                    for (int c = 0; c < 4; ++c)
                        acc[g][r][c] = fmaf(ar[r], br[c], acc[g][r][c]);
            }
        }
        // 4. one barrier per tile
        __syncthreads();
    }

    // ---- epilogue: cell update (i,f,g,o gate order)
    const int j = j0 + tx * 4;
    float4 bi0 = ld4(bih + 0*H_ + j), bi1 = ld4(bih + 1*H_ + j);
    float4 bi2 = ld4(bih + 2*H_ + j), bi3 = ld4(bih + 3*H_ + j);
    float4 bh0 = ld4(bhh + 0*H_ + j), bh1 = ld4(bhh + 1*H_ + j);
    float4 bh2 = ld4(bhh + 2*H_ + j), bh3 = ld4(bhh + 3*H_ + j);
    float bi[4][4] = {{bi0.x,bi0.y,bi0.z,bi0.w},{bi1.x,bi1.y,bi1.z,bi1.w},
                      {bi2.x,bi2.y,bi2.z,bi2.w},{bi3.x,bi3.y,bi3.z,bi3.w}};
    float bh[4][4] = {{bh0.x,bh0.y,bh0.z,bh0.w},{bh1.x,bh1.y,bh1.z,bh1.w},
                      {bh2.x,bh2.y,bh2.z,bh2.w},{bh3.x,bh3.y,bh3.z,bh3.w}};

#pragma unroll
    for (int r = 0; r < 8; ++r) {
        const int b = b0 + ty * 8 + r;
        float4 c4 = ld4(Cst + (size_t)b * H_ + j);
        float cold[4] = {c4.x, c4.y, c4.z, c4.w};
        float cn[4], hn[4];
#pragma unroll
        for (int c = 0; c < 4; ++c) {
            float gi = acc[0][r][c] + bi[0][c] + bh[0][c];
            float gf = acc[1][r][c] + bi[1][c] + bh[1][c];
            float gg = acc[2][r][c] + bi[2][c] + bh[2][c];
            float go = acc[3][r][c] + bi[3][c] + bh[3][c];
            float si = sigm(gi), sf = sigm(gf), so = sigm(go);
            float tg = tanhf(gg);
            // keep mul/add separate (no fma contraction) to mirror XLA elementwise
            float cc = __fadd_rn(__fmul_rn(sf, cold[c]), __fmul_rn(si, tg));
            cn[c] = cc;
            hn[c] = __fmul_rn(so, tanhf(cc));
        }
        float4 co = {cn[0], cn[1], cn[2], cn[3]};
        float4 ho = {hn[0], hn[1], hn[2], hn[3]};
        *reinterpret_cast<float4*>(Cst  + (size_t)b * H_ + j) = co;
        *reinterpret_cast<float4*>(Hout + (size_t)b * H_ + j) = ho;
    }
}

// ---------------------------------------------------------------------------
// logits = h1 @ W_out^T + b_out ; gumbel-argmax sampling (JAX categorical),
// EOS / PAD bookkeeping, token output. 64 rows per block.
// RNG: threefry partitionable mode (JAX >= 0.4.36 default).
// ---------------------------------------------------------------------------
__global__ __launch_bounds__(256)
void sample_step(const float* __restrict__ H1src, const float* __restrict__ Wout,
                 const float* __restrict__ bout,
                 int* __restrict__ prevtok, int* __restrict__ isend,
                 int* __restrict__ out, int t, int T)
{
    __shared__ __align__(16) float As[16][68];
    __shared__ __align__(16) float Bs[16][68];
    __shared__ float LG[64][65];

    const int tid  = threadIdx.x;
    const int b0   = blockIdx.x * 64;
    const int tx   = tid & 15, ty = tid >> 4;
    const int lrow = tid >> 2, lkq = tid & 3;

    float acc[4][4] = {};

    for (int kt = 0; kt < H_ / 16; ++kt) {
        const int k0 = kt * 16;
        float4 av = ld4(H1src + (size_t)(b0 + lrow) * H_ + k0 + lkq * 4);
        float4 bv = ld4(Wout  + (size_t)lrow * H_ + k0 + lkq * 4);
        __syncthreads();
        As[lkq*4+0][lrow] = av.x; As[lkq*4+1][lrow] = av.y; As[lkq*4+2][lrow] = av.z; As[lkq*4+3][lrow] = av.w;
        Bs[lkq*4+0][lrow] = bv.x; Bs[lkq*4+1][lrow] = bv.y; Bs[lkq*4+2][lrow] = bv.z; Bs[lkq*4+3][lrow] = bv.w;
        __syncthreads();
#pragma unroll
        for (int kk = 0; kk < 16; ++kk) {
            float4 a4 = ld4(&As[kk][ty*4]);
            float4 b4 = ld4(&Bs[kk][tx*4]);
            float ar[4] = {a4.x, a4.y, a4.z, a4.w};
            float br[4] = {b4.x, b4.y, b4.z, b4.w};
#pragma unroll
            for (int r = 0; r < 4; ++r)
#pragma unroll
                for (int c = 0; c < 4; ++c)
                    acc[r][c] = fmaf(ar[r], br[c], acc[r][c]);
        }
    }

#pragma unroll
    for (int r = 0; r < 4; ++r)
#pragma unroll
        for (int c = 0; c < 4; ++c)
            LG[ty*4 + r][tx*4 + c] = acc[r][c] + bout[tx*4 + c];
    __syncthreads();

    const int wv = tid >> 6, lane = tid & 63;
    uint32_t kt0, kt1;
    tf2x32(0u, 42u, 0u, (uint32_t)t, kt0, kt1);   // fold-like split of key(42)

    const float TINY = 1.1754943508222875e-38f;   // finfo(f32).tiny
    for (int rr = 0; rr < 16; ++rr) {
        const int r = wv * 16 + rr;
        const int b = b0 + r;
        float lg = LG[r][lane];
        uint32_t r0, r1;
        tf2x32(kt0, kt1, 0u, (uint32_t)(b * V_ + lane), r0, r1);
        uint32_t bits = r0 ^ r1;                  // partitionable 32-bit fold
        float f = __uint_as_float((bits >> 9) | 0x3f800000u) - 1.0f;
        float u = fmaxf(TINY, __fadd_rn(f, TINY));
        float g = -logf(-logf(u));
        float val = __fadd_rn(g, lg);
        int idx = lane;
#pragma unroll
        for (int off = 32; off > 0; off >>= 1) {
            float ov = __shfl_xor(val, off, 64);
            int   oi = __shfl_xor(idx, off, 64);
            if (ov > val || (ov == val && oi < idx)) { val = ov; idx = oi; }
        }
        if (lane == 0) {
            int cur = idx;
            int e   = isend[b];
            int en  = e | (cur == EOS_);
            int tok = en ? PAD_ : cur;
            isend[b]   = en;
            prevtok[b] = tok;
            out[(size_t)b * T + t] = tok;
        }
    }
}

// ---------------------------------------------------------------------------
extern "C" void kernel_launch(void* const* d_in, const int* in_sizes, int n_in,
                              void* d_out, int out_size, void* d_ws, size_t ws_size,
                              hipStream_t stream)
{
    (void)in_sizes; (void)n_in; (void)ws_size;
    const float* z    = (const float*)d_in[0];
    const float* E    = (const float*)d_in[1];
    const float* Wl2h = (const float*)d_in[2];
    const float* bl2h = (const float*)d_in[3];
    const float* Wih0 = (const float*)d_in[4];
    const float* Whh0 = (const float*)d_in[5];
    const float* bih0 = (const float*)d_in[6];
    const float* bhh0 = (const float*)d_in[7];
    const float* Wih1 = (const float*)d_in[8];
    const float* Whh1 = (const float*)d_in[9];
    const float* bih1 = (const float*)d_in[10];
    const float* bhh1 = (const float*)d_in[11];
    const float* Wout = (const float*)d_in[12];
    const float* bout = (const float*)d_in[13];
    int* out = (int*)d_out;
    const int T = out_size / B_;   // 100

    char* w = (char*)d_ws;
    const size_t S = (size_t)B_ * H_ * sizeof(float);   // 33.55 MB
    float* C0  = (float*)(w + 0 * S);
    float* C1  = (float*)(w + 1 * S);
    float* H0A = (float*)(w + 2 * S);
    float* H0B = (float*)(w + 3 * S);
    float* H1A = (float*)(w + 4 * S);
    float* H1B = (float*)(w + 5 * S);
    int* prevtok = (int*)(w + 6 * S);
    int* isend   = (int*)(w + 6 * S + (size_t)B_ * sizeof(int));

    dim3 blk(256);
    init_state<<<dim3(B_/64, H_/64), blk, 0, stream>>>(z, Wl2h, bl2h, C0, C1, H0A, H1A);
    init_tokens<<<dim3(B_/256), blk, 0, stream>>>(prevtok, isend);

    float *h0c = H0A, *h0n = H0B, *h1c = H1A, *h1n = H1B;
    for (int t = 0; t < T; ++t) {
        lstm_layer<DEMB_, true><<<dim3((B_/128) * 8), blk, 0, stream>>>(
            E, prevtok, h0c, Wih0, Whh0, bih0, bhh0, C0, h0n);
        lstm_layer<H_, false><<<dim3((B_/128) * 8), blk, 0, stream>>>(
            h0n, nullptr, h1c, Wih1, Whh1, bih1, bhh1, C1, h1n);
        sample_step<<<dim3(B_/64), blk, 0, stream>>>(
            h1n, Wout, bout, prevtok, isend, out, t, T);
        float* tmp;
        tmp = h0c; h0c = h0n; h0n = tmp;
        tmp = h1c; h1c = h1n; h1n = tmp;
    }
}

// Round 4
// 128416.748 us; speedup vs baseline: 1.0724x; 1.0285x over previous
//
#include <hip/hip_runtime.h>
#include <stdint.h>

// Problem constants (from reference)
#define B_    16384
#define V_    64
#define DEMB_ 128
#define H_    512
#define PAD_  0
#define BOS_  1
#define EOS_  2

__device__ __forceinline__ uint32_t rotl32(uint32_t v, int n) {
    return (v << n) | (v >> (32 - n));
}

// JAX threefry2x32 (20 rounds), matches jax/_src/prng.py exactly.
__device__ __forceinline__ void tf2x32(uint32_t k0, uint32_t k1,
                                       uint32_t x0, uint32_t x1,
                                       uint32_t& o0, uint32_t& o1)
{
    const uint32_t k2 = k0 ^ k1 ^ 0x1BD11BDAu;
    x0 += k0; x1 += k1;
#define TFR(r) { x0 += x1; x1 = rotl32(x1, (r)); x1 ^= x0; }
    TFR(13) TFR(15) TFR(26) TFR(6)
    x0 += k1; x1 += k2 + 1u;
    TFR(17) TFR(29) TFR(16) TFR(24)
    x0 += k2; x1 += k0 + 2u;
    TFR(13) TFR(15) TFR(26) TFR(6)
    x0 += k0; x1 += k1 + 3u;
    TFR(17) TFR(29) TFR(16) TFR(24)
    x0 += k1; x1 += k2 + 4u;
    TFR(13) TFR(15) TFR(26) TFR(6)
    x0 += k2; x1 += k0 + 5u;
#undef TFR
    o0 = x0; o1 = x1;
}

__device__ __forceinline__ float sigm(float x) {
    return 1.0f / (1.0f + expf(-x));
}

__device__ __forceinline__ float4 ld4(const float* p) {
    return *reinterpret_cast<const float4*>(p);
}
__device__ __forceinline__ float2 ld2(const float* p) {
    return *reinterpret_cast<const float2*>(p);
}

// ---------------------------------------------------------------------------
// init: C0 = C1 = z @ W_l2h^T + b_l2h ; H0 = H1 = 0
// ---------------------------------------------------------------------------
__global__ __launch_bounds__(256)
void init_state(const float* __restrict__ z, const float* __restrict__ Wl,
                const float* __restrict__ bl,
                float* __restrict__ C0, float* __restrict__ C1,
                float* __restrict__ H0, float* __restrict__ H1)
{
    __shared__ __align__(16) float As[16][68];
    __shared__ __align__(16) float Bs[16][68];
    const int tid  = threadIdx.x;
    const int b0   = blockIdx.x * 64;
    const int j0   = blockIdx.y * 64;
    const int tx   = tid & 15, ty = tid >> 4;
    const int lrow = tid >> 2, lkq = tid & 3;

    float acc[4][4] = {};

    for (int kt = 0; kt < DEMB_ / 16; ++kt) {
        const int k0 = kt * 16;
        float4 av = ld4(z  + (size_t)(b0 + lrow) * DEMB_ + k0 + lkq * 4);
        float4 bv = ld4(Wl + (size_t)(j0 + lrow) * DEMB_ + k0 + lkq * 4);
        __syncthreads();
        As[lkq*4+0][lrow] = av.x; As[lkq*4+1][lrow] = av.y; As[lkq*4+2][lrow] = av.z; As[lkq*4+3][lrow] = av.w;
        Bs[lkq*4+0][lrow] = bv.x; Bs[lkq*4+1][lrow] = bv.y; Bs[lkq*4+2][lrow] = bv.z; Bs[lkq*4+3][lrow] = bv.w;
        __syncthreads();
#pragma unroll
        for (int kk = 0; kk < 16; ++kk) {
            float4 a4 = ld4(&As[kk][ty*4]);
            float4 b4 = ld4(&Bs[kk][tx*4]);
            float ar[4] = {a4.x, a4.y, a4.z, a4.w};
            float br[4] = {b4.x, b4.y, b4.z, b4.w};
#pragma unroll
            for (int r = 0; r < 4; ++r)
#pragma unroll
                for (int c = 0; c < 4; ++c)
                    acc[r][c] = fmaf(ar[r], br[c], acc[r][c]);
        }
    }

#pragma unroll
    for (int r = 0; r < 4; ++r) {
        const int b = b0 + ty * 4 + r;
        const int j = j0 + tx * 4;
        float4 cv = {acc[r][0] + bl[j+0], acc[r][1] + bl[j+1],
                     acc[r][2] + bl[j+2], acc[r][3] + bl[j+3]};
        float4 zz = {0.f, 0.f, 0.f, 0.f};
        *reinterpret_cast<float4*>(C0 + (size_t)b * H_ + j) = cv;
        *reinterpret_cast<float4*>(C1 + (size_t)b * H_ + j) = cv;
        *reinterpret_cast<float4*>(H0 + (size_t)b * H_ + j) = zz;
        *reinterpret_cast<float4*>(H1 + (size_t)b * H_ + j) = zz;
    }
}

__global__ __launch_bounds__(256)
void init_tokens(int* __restrict__ prevtok, int* __restrict__ isend)
{
    int i = blockIdx.x * 256 + threadIdx.x;
    if (i < B_) { prevtok[i] = BOS_; isend[i] = 0; }
}

// ---------------------------------------------------------------------------
// XW0[v][n] = sum_k E[v,k] * Wih0[n,k]  (fmaf chain, k ascending ->
// bit-identical to the x-partial of the original fused gate chain).
// v in [0,64), n = g*512+unit in [0,2048).
// ---------------------------------------------------------------------------
__global__ __launch_bounds__(256)
void build_xw0(const float* __restrict__ E, const float* __restrict__ Wih0,
               float* __restrict__ XW0)
{
    const int idx = blockIdx.x * 256 + threadIdx.x;   // 0 .. 64*2048-1
    const int v = idx >> 11;
    const int n = idx & 2047;
    const float* e = E + (size_t)v * DEMB_;
    const float* w = Wih0 + (size_t)n * DEMB_;
    float acc = 0.f;
    for (int k = 0; k < DEMB_; ++k)
        acc = fmaf(e[k], w[k], acc);
    XW0[(size_t)v * 2048 + n] = acc;
}

// ---------------------------------------------------------------------------
// Fused LSTM layer, deep-pipelined (R3 structure):
//   - 128 batch rows x 64 units x 4 gates per block, 256 threads, acc 4x8x4.
//   - double-buffered LDS, ONE __syncthreads per K-tile, prefetch 2 deep.
//   - XCD swizzle: j-block = bid&7.
//   - XW=true (layer 0): acc initialized from XW0[token] gather (bit-identical
//     to running the x-GEMM: same fmaf chain), k-loop covers Hrec only (KX=0).
//   - XW=false (layer 1): KX=512, A = [h0 | Hrec] as before.
// ---------------------------------------------------------------------------
template<int KX, bool XW>
__global__ __launch_bounds__(256, 2)
void lstm_layer(const float* __restrict__ Asrc,
                const int*   __restrict__ prevtok,
                const float* __restrict__ XW0,
                const float* __restrict__ Hrec,
                const float* __restrict__ Wih,   // [2048, KX] (unused if XW)
                const float* __restrict__ Whh,   // [2048, 512]
                const float* __restrict__ bih,
                const float* __restrict__ bhh,
                float* __restrict__ Cst,
                float* __restrict__ Hout)
{
    __shared__ __align__(16) float As[2][16][132];     // [buf][k][row]
    __shared__ __align__(16) float Bs[2][4][16][68];   // [buf][gate][k][unit]
    __shared__ int rowtok[128];

    const int tid  = threadIdx.x;
    const int bid  = blockIdx.x;
    const int b0   = (bid >> 3) * 128;     // batch block
    const int j0   = (bid & 7) * 64;       // unit block -> XCD-affine
    const int tx   = tid & 15;             // col group (4 units)
    const int ty   = tid >> 4;             // row group (8 rows)
    const int srow = tid >> 1;             // staging row 0..127
    const int sk   = (tid & 1) * 8;        // staging k-half

    if (XW) {
        if (tid < 128) rowtok[tid] = prevtok[b0 + tid];
        __syncthreads();
    }

    // staging role: this thread loads weight rows (g0,u0) and (g1,u1)
    const int grow0 = srow, grow1 = srow + 128;
    const int g0 = grow0 >> 6, u0 = grow0 & 63;
    const int g1 = grow1 >> 6, u1 = grow1 & 63;

    const float* arowA = (KX > 0) ? (Asrc + (size_t)(b0 + srow) * KX) : nullptr;
    const float* arowH = Hrec + (size_t)(b0 + srow) * H_;
    const float* browA0 = (KX > 0) ? (Wih + (size_t)(g0 * H_ + j0 + u0) * KX) : nullptr;
    const float* browA1 = (KX > 0) ? (Wih + (size_t)(g1 * H_ + j0 + u1) * KX) : nullptr;
    const float* browH0 = Whh + (size_t)(g0 * H_ + j0 + u0) * H_;
    const float* browH1 = Whh + (size_t)(g1 * H_ + j0 + u1) * H_;

    const int NT = (KX + H_) / 16;

    float4 av[2], bv[4];

    auto load_tile = [&](int kt) {
        const int k0 = kt * 16;
        if (KX > 0 && k0 < KX) {
            av[0] = ld4(arowA + k0 + sk);
            av[1] = ld4(arowA + k0 + sk + 4);
            bv[0] = ld4(browA0 + k0 + sk);
            bv[1] = ld4(browA0 + k0 + sk + 4);
            bv[2] = ld4(browA1 + k0 + sk);
            bv[3] = ld4(browA1 + k0 + sk + 4);
        } else {
            const int kh = k0 - KX;
            av[0] = ld4(arowH + kh + sk);
            av[1] = ld4(arowH + kh + sk + 4);
            bv[0] = ld4(browH0 + kh + sk);
            bv[1] = ld4(browH0 + kh + sk + 4);
            bv[2] = ld4(browH1 + kh + sk);
            bv[3] = ld4(browH1 + kh + sk + 4);
        }
    };

    auto write_tile = [&](int p) {
        float a0[4] = {av[0].x, av[0].y, av[0].z, av[0].w};
        float a1[4] = {av[1].x, av[1].y, av[1].z, av[1].w};
#pragma unroll
        for (int i = 0; i < 4; ++i) {
            As[p][sk + i][srow]     = a0[i];
            As[p][sk + 4 + i][srow] = a1[i];
        }
        float b0r[4] = {bv[0].x, bv[0].y, bv[0].z, bv[0].w};
        float b1r[4] = {bv[1].x, bv[1].y, bv[1].z, bv[1].w};
        float b2r[4] = {bv[2].x, bv[2].y, bv[2].z, bv[2].w};
        float b3r[4] = {bv[3].x, bv[3].y, bv[3].z, bv[3].w};
#pragma unroll
        for (int i = 0; i < 4; ++i) {
            Bs[p][g0][sk + i][u0]     = b0r[i];
            Bs[p][g0][sk + 4 + i][u0] = b1r[i];
            Bs[p][g1][sk + i][u1]     = b2r[i];
            Bs[p][g1][sk + 4 + i][u1] = b3r[i];
        }
    };

    // ---- accumulator init: zeros, or XW0 gather (layer 0)
    float acc[4][8][4];
    if (XW) {
#pragma unroll
        for (int r = 0; r < 8; ++r) {
            const int tok = rowtok[ty * 8 + r];
            const float* xr = XW0 + (size_t)tok * 2048 + j0 + tx * 4;
#pragma unroll
            for (int g = 0; g < 4; ++g) {
                float4 x4 = ld4(xr + g * H_);
                acc[g][r][0] = x4.x; acc[g][r][1] = x4.y;
                acc[g][r][2] = x4.z; acc[g][r][3] = x4.w;
            }
        }
    } else {
#pragma unroll
        for (int g = 0; g < 4; ++g)
#pragma unroll
            for (int r = 0; r < 8; ++r)
#pragma unroll
                for (int c = 0; c < 4; ++c)
                    acc[g][r][c] = 0.f;
    }

    // ---- prologue: tile0 -> buf0; issue tile1 loads; barrier
    load_tile(0);
    write_tile(0);
    load_tile(1);
    __syncthreads();

    for (int kt = 0; kt < NT; ++kt) {
        const int cur = kt & 1;
        if (kt + 1 < NT) {
            write_tile(cur ^ 1);
            if (kt + 2 < NT) load_tile(kt + 2);
        }
#pragma unroll 4
        for (int kk = 0; kk < 16; ++kk) {
            float4 a40 = ld4(&As[cur][kk][ty*8]);
            float4 a41 = ld4(&As[cur][kk][ty*8+4]);
            float ar[8] = {a40.x, a40.y, a40.z, a40.w, a41.x, a41.y, a41.z, a41.w};
#pragma unroll
            for (int g = 0; g < 4; ++g) {
                float4 b4 = ld4(&Bs[cur][g][kk][tx*4]);
                float br[4] = {b4.x, b4.y, b4.z, b4.w};
#pragma unroll
                for (int r = 0; r < 8; ++r)
#pragma unroll
                    for (int c = 0; c < 4; ++c)
                        acc[g][r][c] = fmaf(ar[r], br[c], acc[g][r][c]);
            }
        }
        __syncthreads();
    }

    // ---- epilogue: cell update (i,f,g,o gate order)
    const int j = j0 + tx * 4;
    float4 bi0 = ld4(bih + 0*H_ + j), bi1 = ld4(bih + 1*H_ + j);
    float4 bi2 = ld4(bih + 2*H_ + j), bi3 = ld4(bih + 3*H_ + j);
    float4 bh0 = ld4(bhh + 0*H_ + j), bh1 = ld4(bhh + 1*H_ + j);
    float4 bh2 = ld4(bhh + 2*H_ + j), bh3 = ld4(bhh + 3*H_ + j);
    float bi[4][4] = {{bi0.x,bi0.y,bi0.z,bi0.w},{bi1.x,bi1.y,bi1.z,bi1.w},
                      {bi2.x,bi2.y,bi2.z,bi2.w},{bi3.x,bi3.y,bi3.z,bi3.w}};
    float bh[4][4] = {{bh0.x,bh0.y,bh0.z,bh0.w},{bh1.x,bh1.y,bh1.z,bh1.w},
                      {bh2.x,bh2.y,bh2.z,bh2.w},{bh3.x,bh3.y,bh3.z,bh3.w}};

#pragma unroll
    for (int r = 0; r < 8; ++r) {
        const int b = b0 + ty * 8 + r;
        float4 c4 = ld4(Cst + (size_t)b * H_ + j);
        float cold[4] = {c4.x, c4.y, c4.z, c4.w};
        float cn[4], hn[4];
#pragma unroll
        for (int c = 0; c < 4; ++c) {
            float gi = acc[0][r][c] + bi[0][c] + bh[0][c];
            float gf = acc[1][r][c] + bi[1][c] + bh[1][c];
            float gg = acc[2][r][c] + bi[2][c] + bh[2][c];
            float go = acc[3][r][c] + bi[3][c] + bh[3][c];
            float si = sigm(gi), sf = sigm(gf), so = sigm(go);
            float tg = tanhf(gg);
            // keep mul/add separate (no fma contraction) to mirror XLA elementwise
            float cc = __fadd_rn(__fmul_rn(sf, cold[c]), __fmul_rn(si, tg));
            cn[c] = cc;
            hn[c] = __fmul_rn(so, tanhf(cc));
        }
        float4 co = {cn[0], cn[1], cn[2], cn[3]};
        float4 ho = {hn[0], hn[1], hn[2], hn[3]};
        *reinterpret_cast<float4*>(Cst  + (size_t)b * H_ + j) = co;
        *reinterpret_cast<float4*>(Hout + (size_t)b * H_ + j) = ho;
    }
}

// ---------------------------------------------------------------------------
// logits = h1 @ W_out^T + b_out ; gumbel-argmax sampling (JAX categorical).
// 32 rows per block, 512 blocks -> 2 blocks/CU, 2 waves/SIMD.
// Pipelined like the lstm kernels: dbuf LDS, 1 barrier/tile, prefetch 2.
// Per-row math (fmaf chain k ascending, bias, gumbel, 64-lane reduce) is
// instruction-identical to the passing rounds -> bit-identical output.
// ---------------------------------------------------------------------------
__global__ __launch_bounds__(256, 2)
void sample_step(const float* __restrict__ H1src, const float* __restrict__ Wout,
                 const float* __restrict__ bout,
                 int* __restrict__ prevtok, int* __restrict__ isend,
                 int* __restrict__ out, int t, int T)
{
    __shared__ __align__(16) float As[2][16][36];   // [buf][k][row(32)]
    __shared__ __align__(16) float Bs[2][16][68];   // [buf][k][vocab(64)]
    __shared__ float LG[32][65];

    const int tid  = threadIdx.x;
    const int b0   = blockIdx.x * 32;
    const int tx   = tid & 15, ty = tid >> 4;       // cols 4x, rows 2x
    const int arow = tid >> 3, ak = (tid & 7) * 2;  // A-stage: 32 rows x 16 k
    const int brow = tid >> 2, bk = (tid & 3) * 4;  // B-stage: 64 rows x 16 k

    const float* aptr = H1src + (size_t)(b0 + arow) * H_;
    const float* bptr = Wout  + (size_t)brow * H_;

    float2 av;
    float4 bv;
    auto load_tile = [&](int kt) {
        const int k0 = kt * 16;
        av = ld2(aptr + k0 + ak);
        bv = ld4(bptr + k0 + bk);
    };
    auto write_tile = [&](int p) {
        As[p][ak + 0][arow] = av.x;
        As[p][ak + 1][arow] = av.y;
        float br[4] = {bv.x, bv.y, bv.z, bv.w};
#pragma unroll
        for (int i = 0; i < 4; ++i) Bs[p][bk + i][brow] = br[i];
    };

    float acc[2][4] = {};

    load_tile(0);
    write_tile(0);
    load_tile(1);
    __syncthreads();

    const int NT = H_ / 16;   // 32
    for (int kt = 0; kt < NT; ++kt) {
        const int cur = kt & 1;
        if (kt + 1 < NT) {
            write_tile(cur ^ 1);
            if (kt + 2 < NT) load_tile(kt + 2);
        }
#pragma unroll 4
        for (int kk = 0; kk < 16; ++kk) {
            float2 a2 = ld2(&As[cur][kk][ty*2]);
            float4 b4 = ld4(&Bs[cur][kk][tx*4]);
            float ar[2] = {a2.x, a2.y};
            float br[4] = {b4.x, b4.y, b4.z, b4.w};
#pragma unroll
            for (int r = 0; r < 2; ++r)
#pragma unroll
                for (int c = 0; c < 4; ++c)
                    acc[r][c] = fmaf(ar[r], br[c], acc[r][c]);
        }
        __syncthreads();
    }

#pragma unroll
    for (int r = 0; r < 2; ++r)
#pragma unroll
        for (int c = 0; c < 4; ++c)
            LG[ty*2 + r][tx*4 + c] = acc[r][c] + bout[tx*4 + c];
    __syncthreads();

    const int wv = tid >> 6, lane = tid & 63;
    uint32_t kt0, kt1;
    tf2x32(0u, 42u, 0u, (uint32_t)t, kt0, kt1);   // fold-like split of key(42)

    const float TINY = 1.1754943508222875e-38f;   // finfo(f32).tiny
    for (int rr = 0; rr < 8; ++rr) {
        const int r = wv * 8 + rr;
        const int b = b0 + r;
        float lg = LG[r][lane];
        uint32_t r0, r1;
        tf2x32(kt0, kt1, 0u, (uint32_t)(b * V_ + lane), r0, r1);
        uint32_t bits = r0 ^ r1;                  // partitionable 32-bit fold
        float f = __uint_as_float((bits >> 9) | 0x3f800000u) - 1.0f;
        float u = fmaxf(TINY, __fadd_rn(f, TINY));
        float g = -logf(-logf(u));
        float val = __fadd_rn(g, lg);
        int idx = lane;
#pragma unroll
        for (int off = 32; off > 0; off >>= 1) {
            float ov = __shfl_xor(val, off, 64);
            int   oi = __shfl_xor(idx, off, 64);
            if (ov > val || (ov == val && oi < idx)) { val = ov; idx = oi; }
        }
        if (lane == 0) {
            int cur = idx;
            int e   = isend[b];
            int en  = e | (cur == EOS_);
            int tok = en ? PAD_ : cur;
            isend[b]   = en;
            prevtok[b] = tok;
            out[(size_t)b * T + t] = tok;
        }
    }
}

// ---------------------------------------------------------------------------
extern "C" void kernel_launch(void* const* d_in, const int* in_sizes, int n_in,
                              void* d_out, int out_size, void* d_ws, size_t ws_size,
                              hipStream_t stream)
{
    (void)in_sizes; (void)n_in; (void)ws_size;
    const float* z    = (const float*)d_in[0];
    const float* E    = (const float*)d_in[1];
    const float* Wl2h = (const float*)d_in[2];
    const float* bl2h = (const float*)d_in[3];
    const float* Wih0 = (const float*)d_in[4];
    const float* Whh0 = (const float*)d_in[5];
    const float* bih0 = (const float*)d_in[6];
    const float* bhh0 = (const float*)d_in[7];
    const float* Wih1 = (const float*)d_in[8];
    const float* Whh1 = (const float*)d_in[9];
    const float* bih1 = (const float*)d_in[10];
    const float* bhh1 = (const float*)d_in[11];
    const float* Wout = (const float*)d_in[12];
    const float* bout = (const float*)d_in[13];
    int* out = (int*)d_out;
    const int T = out_size / B_;   // 100

    char* w = (char*)d_ws;
    const size_t S = (size_t)B_ * H_ * sizeof(float);   // 33.55 MB
    float* C0  = (float*)(w + 0 * S);
    float* C1  = (float*)(w + 1 * S);
    float* H0A = (float*)(w + 2 * S);
    float* H0B = (float*)(w + 3 * S);
    float* H1A = (float*)(w + 4 * S);
    float* H1B = (float*)(w + 5 * S);
    int* prevtok = (int*)(w + 6 * S);
    int* isend   = (int*)(w + 6 * S + (size_t)B_ * sizeof(int));
    float* XW0   = (float*)(w + 6 * S + 2 * (size_t)B_ * sizeof(int));  // 64x2048

    dim3 blk(256);
    init_state<<<dim3(B_/64, H_/64), blk, 0, stream>>>(z, Wl2h, bl2h, C0, C1, H0A, H1A);
    init_tokens<<<dim3(B_/256), blk, 0, stream>>>(prevtok, isend);
    build_xw0<<<dim3(64 * 2048 / 256), blk, 0, stream>>>(E, Wih0, XW0);

    float *h0c = H0A, *h0n = H0B, *h1c = H1A, *h1n = H1B;
    for (int t = 0; t < T; ++t) {
        lstm_layer<0, true><<<dim3((B_/128) * 8), blk, 0, stream>>>(
            nullptr, prevtok, XW0, h0c, nullptr, Whh0, bih0, bhh0, C0, h0n);
        lstm_layer<H_, false><<<dim3((B_/128) * 8), blk, 0, stream>>>(
            h0n, nullptr, nullptr, h1c, Wih1, Whh1, bih1, bhh1, C1, h1n);
        sample_step<<<dim3(B_/32), blk, 0, stream>>>(
            h1n, Wout, bout, prevtok, isend, out, t, T);
        float* tmp;
        tmp = h0c; h0c = h0n; h0n = tmp;
        tmp = h1c; h1c = h1n; h1n = tmp;
    }
}